// Round 4
// baseline (496.545 us; speedup 1.0000x reference)
//
#include <hip/hip_runtime.h>

typedef __attribute__((ext_vector_type(8)))  short short8;
typedef __attribute__((ext_vector_type(4)))  float f32x4;
typedef __attribute__((ext_vector_type(16))) float f32x16;

#define L2E 1.44269504088896340736f

__device__ __forceinline__ unsigned short f2bf(float x) {
    union { float f; unsigned int u; } v; v.f = x;
    unsigned int u = v.u;
    unsigned int r = (u + 0x7FFFu + ((u >> 16) & 1u)) >> 16;
    return (unsigned short)r;
}

__device__ __forceinline__ float mishf(float x) {
    float u = __builtin_amdgcn_exp2f(x * L2E);
    float t = u * (u + 2.0f);
    return x * t * __builtin_amdgcn_rcpf(t + 2.0f);
}

// masked p = adj_bit * exp(mish(s1+s2)); log2-domain inputs (pre-scaled by log2 e),
// u = e^{s1} * e^{s2} from precomputed factors (2 transcendentals total).
__device__ __forceinline__ short pw2(unsigned int mby, int j, float svL, float ev,
                                     float s1v, float e1v) {
    float xL = s1v + svL;
    float u  = e1v * ev;
    float t  = u * (u + 2.0f);
    float m  = xL * t * __builtin_amdgcn_rcpf(t + 2.0f);
    float p  = __builtin_amdgcn_exp2f(m);
    union { float f; unsigned int u; } b; b.f = p;
    unsigned short h = (unsigned short)((b.u + 0x8000u) >> 16);
    return ((mby >> j) & 1u) ? (short)h : (short)0;
}

typedef __attribute__((address_space(1))) const unsigned int guint;
typedef __attribute__((address_space(3))) unsigned int luint;
__device__ __forceinline__ void lds16(const void* g, void* l) {
    __builtin_amdgcn_global_load_lds((guint*)g, (luint*)l, 16, 0, 0);
}
__device__ __forceinline__ void lds4(const void* g, void* l) {
    __builtin_amdgcn_global_load_lds((guint*)g, (luint*)l, 4, 0, 0);
}

// ---------------- adj (0/1 f32, 256 MB) -> bitmask (8 MB), streaming ----------
__global__ __launch_bounds__(256) void k_pack(const float* __restrict__ adj,
                                              unsigned int* __restrict__ mask) {
    int wid = blockIdx.x * 4 + (threadIdx.x >> 6);   // one wave per row
    int lane = threadIdx.x & 63;
    const float* row = adj + (size_t)wid * 8192 + lane;
    unsigned int* mrow = mask + wid * 256;
#pragma unroll 2
    for (int base = 0; base < 8192; base += 256) {
        float v0 = row[base];
        float v1 = row[base + 64];
        float v2 = row[base + 128];
        float v3 = row[base + 192];
        unsigned long long b0 = __ballot(v0 > 0.5f);
        unsigned long long b1 = __ballot(v1 > 0.5f);
        unsigned long long b2 = __ballot(v2 > 0.5f);
        unsigned long long b3 = __ballot(v3 > 0.5f);
        if (lane == 0) {
            *(ulonglong2*)(mrow + (base >> 5))     = make_ulonglong2(b0, b1);
            *(ulonglong2*)(mrow + (base >> 5) + 4) = make_ulonglong2(b2, b3);
        }
    }
}

// ---------------- kernel: W (512x256 f32) -> WT bf16 (256x512) ----------------
__global__ void k_cvt_wt(const float* __restrict__ W, unsigned short* __restrict__ wt) {
    int c = blockIdx.x;
    int t = threadIdx.x;
    wt[c * 512 + t]       = f2bf(W[(size_t)t * 256 + c]);
    wt[c * 512 + t + 256] = f2bf(W[(size_t)(t + 256) * 256 + c]);
}

// ------- h = input @ W (bf16 MFMA) fused with s1/s2/e2 epilogue ---------------
__global__ __launch_bounds__(256) void k_gemm_h(const float* __restrict__ input,
                                                const unsigned short* __restrict__ wt,
                                                const float* __restrict__ a,
                                                unsigned short* __restrict__ hbt,
                                                float* __restrict__ s1L,
                                                float* __restrict__ s2L,
                                                float* __restrict__ e2g) {
    __shared__ float red[2][4][16];
    int tid = threadIdx.x;
    int w = tid >> 6, lane = tid & 63, g = lane >> 4, r = lane & 15;
    int base = blockIdx.x * 16;

    f32x4 acc[4];
#pragma unroll
    for (int n = 0; n < 4; ++n) acc[n] = (f32x4)0.0f;

    const float* arow = input + (size_t)(base + r) * 512 + g * 8;
    const unsigned short* wp = wt + (size_t)(w * 64 + r) * 512 + g * 8;
#pragma unroll 4
    for (int kb = 0; kb < 512; kb += 32) {
        float4 a0 = *(const float4*)(arow + kb);
        float4 a1 = *(const float4*)(arow + kb + 4);
        short8 af;
        af[0] = (short)f2bf(a0.x); af[1] = (short)f2bf(a0.y);
        af[2] = (short)f2bf(a0.z); af[3] = (short)f2bf(a0.w);
        af[4] = (short)f2bf(a1.x); af[5] = (short)f2bf(a1.y);
        af[6] = (short)f2bf(a1.z); af[7] = (short)f2bf(a1.w);
#pragma unroll
        for (int n2 = 0; n2 < 4; ++n2) {
            short8 bf = *(const short8*)(wp + n2 * 8192 + kb);
            acc[n2] = __builtin_amdgcn_mfma_f32_16x16x32_bf16(af, bf, acc[n2], 0, 0, 0);
        }
    }
    int rowc = base + g * 4;
#pragma unroll
    for (int n2 = 0; n2 < 4; ++n2) {
        int col = w * 64 + n2 * 16 + r;
        ushort4 pk;
        pk.x = f2bf(acc[n2][0]); pk.y = f2bf(acc[n2][1]);
        pk.z = f2bf(acc[n2][2]); pk.w = f2bf(acc[n2][3]);
        *(ushort4*)(hbt + (size_t)col * 8192 + rowc) = pk;
    }
    float p1[4] = {0,0,0,0}, p2[4] = {0,0,0,0};
#pragma unroll
    for (int n2 = 0; n2 < 4; ++n2) {
        float a1v = a[w * 64 + n2 * 16 + r];
        float a2v = a[256 + w * 64 + n2 * 16 + r];
#pragma unroll
        for (int i = 0; i < 4; ++i) {
            p1[i] += acc[n2][i] * a1v;
            p2[i] += acc[n2][i] * a2v;
        }
    }
#pragma unroll
    for (int off = 8; off >= 1; off >>= 1) {
#pragma unroll
        for (int i = 0; i < 4; ++i) {
            p1[i] += __shfl_xor(p1[i], off);
            p2[i] += __shfl_xor(p2[i], off);
        }
    }
    if (r == 0) {
#pragma unroll
        for (int i = 0; i < 4; ++i) {
            red[0][w][g * 4 + i] = p1[i];
            red[1][w][g * 4 + i] = p2[i];
        }
    }
    __syncthreads();
    if (tid < 16) {
        float s1 = red[0][0][tid] + red[0][1][tid] + red[0][2][tid] + red[0][3][tid];
        float s2 = red[1][0][tid] + red[1][1][tid] + red[1][2][tid] + red[1][3][tid];
        s1L[base + tid] = s1 * L2E;
        float s2l = s2 * L2E;
        s2L[base + tid] = s2l;
        e2g[base + tid] = __builtin_amdgcn_exp2f(s2l);
    }
}

// ---------------- main kernel: superstep-pipelined masked-softmax PV ----------
// 256 blocks (1/CU), 512 thr = 8 waves. Wave = rowgroup (w>>1, 32 rows) x
// feat-half (w&1, 128 feats). MFMA 32x32x16. Superstep = 128 cols: stage
// 64 KB hbt tile (2 bufs), ONE barrier per superstep, prefetch 1 ahead.
__global__ __launch_bounds__(512, 2) void k_attn(const unsigned int* __restrict__ mask,
                                                 const unsigned short* __restrict__ hbt,
                                                 const float* __restrict__ s1L,
                                                 const float* __restrict__ s2Lg,
                                                 const float* __restrict__ e2g,
                                                 float* __restrict__ pS,
                                                 float* __restrict__ pZ) {
    __shared__ __align__(16) unsigned short buf[2][32768]; // 2 x (256 feats x 128 k)
    __shared__ __align__(16) float s2s[2048];
    __shared__ __align__(16) float e2s[2048];

    int tid = threadIdx.x;
    int w = tid >> 6, lane = tid & 63;
    int lo5 = lane & 31, hi = lane >> 5, lo7 = lane & 7;
    int rg = w >> 1, fh = w & 1;
    int bid = blockIdx.x;
    int chunk = (bid & 7) >> 1;                       // XCD-pair -> chunk (bijective)
    int mb = ((bid >> 3) << 1) | (bid & 1);
    int kc = chunk * 2048;
    int rowM = mb * 128 + rg * 32 + lo5;
    float s1v = s1L[rowM];
    float e1v = __builtin_amdgcn_exp2f(s1v);
    const uint4* mk4 = (const uint4*)(mask + (size_t)rowM * 256 + (kc >> 5));

    // staging: thread t, instr j: feat = j*32 + (t>>4); src slot = (t&15)^((t>>4)&7)
    const unsigned short* hsrc = hbt + (size_t)(tid >> 4) * 8192 + kc
                                     + (((tid & 15) ^ ((tid >> 4) & 7)) << 3);
    // s2/e2 slices -> LDS (f32)
    {
        const float* s2src = s2Lg + kc + tid;
        const float* e2src = e2g  + kc + tid;
#pragma unroll
        for (int q = 0; q < 4; ++q) {
            lds4(s2src + q * 512, &s2s[q * 512 + tid]);
            lds4(e2src + q * 512, &e2s[q * 512 + tid]);
        }
    }

    int fb = fh * 32768 + lo5 * 256;                  // byte base of this wave's feats

    f32x16 acc[4];
#pragma unroll
    for (int n = 0; n < 4; ++n) acc[n] = (f32x16)0.0f;
    f32x16 accz = (f32x16)0.0f;

    short8 onef;
    {
        short ov = (lo5 == 0) ? (short)0x3F80 : (short)0;
#pragma unroll
        for (int j = 0; j < 8; ++j) onef[j] = ov;
    }

#define STAGE(ss, p) do {                                                      \
        int kb_ = (ss) * 128;                                                  \
        _Pragma("unroll")                                                      \
        for (int j_ = 0; j_ < 8; ++j_)                                         \
            lds16(hsrc + (size_t)j_ * 262144 + kb_,                            \
                  (char*)&buf[p][0] + j_ * 8192 + tid * 16);                   \
    } while (0)

#define VBAR() do {                                                            \
        asm volatile("s_waitcnt vmcnt(0)" ::: "memory");                       \
        __builtin_amdgcn_sched_barrier(0);                                     \
        __builtin_amdgcn_s_barrier();                                          \
        __builtin_amdgcn_sched_barrier(0);                                     \
    } while (0)

#define COMPUTE(p, MK, ss) do {                                                \
        const char* tb_ = (const char*)&buf[p][0] + fb;                        \
        _Pragma("unroll")                                                      \
        for (int ks = 0; ks < 8; ++ks) {                                       \
            unsigned int wbits = ((ks >> 1) == 0) ? (MK).x :                   \
                                 ((ks >> 1) == 1) ? (MK).y :                   \
                                 ((ks >> 1) == 2) ? (MK).z : (MK).w;           \
            unsigned int mby = (wbits >> (((ks & 1) << 4) + (hi << 3))) & 0xffu;\
            int cb_ = (ss) * 128 + ks * 16 + hi * 8;                           \
            float4 sv0 = *(const float4*)&s2s[cb_];                            \
            float4 sv1 = *(const float4*)&s2s[cb_ + 4];                        \
            float4 ev0 = *(const float4*)&e2s[cb_];                            \
            float4 ev1 = *(const float4*)&e2s[cb_ + 4];                        \
            short8 af;                                                         \
            af[0] = pw2(mby, 0, sv0.x, ev0.x, s1v, e1v);                       \
            af[1] = pw2(mby, 1, sv0.y, ev0.y, s1v, e1v);                       \
            af[2] = pw2(mby, 2, sv0.z, ev0.z, s1v, e1v);                       \
            af[3] = pw2(mby, 3, sv0.w, ev0.w, s1v, e1v);                       \
            af[4] = pw2(mby, 4, sv1.x, ev1.x, s1v, e1v);                       \
            af[5] = pw2(mby, 5, sv1.y, ev1.y, s1v, e1v);                       \
            af[6] = pw2(mby, 6, sv1.z, ev1.z, s1v, e1v);                       \
            af[7] = pw2(mby, 7, sv1.w, ev1.w, s1v, e1v);                       \
            const char* tbb_ = tb_ + ((((ks * 2 + hi) ^ lo7)) << 4);           \
            short8 b0 = *(const short8*)(tbb_);                                \
            short8 b1 = *(const short8*)(tbb_ + 8192);                         \
            short8 b2 = *(const short8*)(tbb_ + 16384);                       \
            short8 b3 = *(const short8*)(tbb_ + 24576);                       \
            acc[0] = __builtin_amdgcn_mfma_f32_32x32x16_bf16(af, b0, acc[0], 0, 0, 0); \
            acc[1] = __builtin_amdgcn_mfma_f32_32x32x16_bf16(af, b1, acc[1], 0, 0, 0); \
            acc[2] = __builtin_amdgcn_mfma_f32_32x32x16_bf16(af, b2, acc[2], 0, 0, 0); \
            acc[3] = __builtin_amdgcn_mfma_f32_32x32x16_bf16(af, b3, acc[3], 0, 0, 0); \
            accz   = __builtin_amdgcn_mfma_f32_32x32x16_bf16(af, onef, accz, 0, 0, 0); \
        }                                                                      \
    } while (0)

    // prologue
    STAGE(0, 0);
    uint4 mkA = mk4[0];
    uint4 mkB;
    VBAR();

    for (int ss = 0; ss < 16; ss += 2) {
        mkB = mk4[ss + 1];
        STAGE(ss + 1, 1);
        COMPUTE(0, mkA, ss);
        VBAR();
        int nx = (ss + 2 < 16) ? (ss + 2) : 15;
        mkA = mk4[nx];
        STAGE(nx, 0);
        COMPUTE(1, mkB, ss + 1);
        VBAR();
    }

    // epilogue: partial S (C layout: col = lane&31, row = (e&3)+8*(e>>2)+4*hi)
    {
        float* ps = pS + ((size_t)chunk << 21)
                  + (size_t)(mb * 128 + rg * 32 + hi * 4) * 256 + fh * 128 + lo5;
#pragma unroll
        for (int n = 0; n < 4; ++n) {
#pragma unroll
            for (int e = 0; e < 16; ++e) {
                int rl = (e & 3) + ((e >> 2) << 3);
                ps[(size_t)rl * 256 + n * 32] = acc[n][e];
            }
        }
    }
    if (fh == 0 && lo5 == 0) {
        float* pz = pZ + chunk * 8192 + mb * 128 + rg * 32 + hi * 4;
#pragma unroll
        for (int e = 0; e < 16; ++e) {
            int rl = (e & 3) + ((e >> 2) << 3);
            pz[rl] = accz[e];
        }
    }
#undef STAGE
#undef VBAR
#undef COMPUTE
}

// ---------------- final: reduce partials, divide, mish ------------------------
__global__ void k_final(const float* __restrict__ pS, const float* __restrict__ pZ,
                        float* __restrict__ out) {
    int i = blockIdx.x;
    int f = threadIdx.x;
    size_t o = (size_t)i * 256 + f;
    float sv = pS[o] + pS[o + (1u << 21)] + pS[o + (2u << 21)] + pS[o + (3u << 21)];
    float z = pZ[i] + pZ[i + 8192] + pZ[i + 16384] + pZ[i + 24576];
    float hp = sv / z;
    out[o] = mishf(hp);
}

extern "C" void kernel_launch(void* const* d_in, const int* in_sizes, int n_in,
                              void* d_out, int out_size, void* d_ws, size_t ws_size,
                              hipStream_t stream) {
    const float* input = (const float*)d_in[0];
    const float* adj   = (const float*)d_in[1];
    const float* W     = (const float*)d_in[2];
    const float* a     = (const float*)d_in[3];
    float* out = (float*)d_out;

    char* ws = (char*)d_ws;
    unsigned short* wt   = (unsigned short*)ws;                // 256 KB
    unsigned short* hbt  = (unsigned short*)(ws + 262144);     // 4 MB
    float* s1L           = (float*)(ws + 4456448);             // 32 KB
    float* s2L           = (float*)(ws + 4489216);             // 32 KB
    float* e2g           = (float*)(ws + 4521984);             // 32 KB
    unsigned int* mask   = (unsigned int*)(ws + 4554752);      // 8 MB
    float* pS            = (float*)(ws + 12943360);            // 32 MB
    float* pZ            = (float*)(ws + 46497792);            // 128 KB (end ~46.6 MB)

    hipLaunchKernelGGL(k_pack, dim3(2048), dim3(256), 0, stream, adj, mask);
    hipLaunchKernelGGL(k_cvt_wt, dim3(256), dim3(256), 0, stream, W, wt);
    hipLaunchKernelGGL(k_gemm_h, dim3(512), dim3(256), 0, stream, input, wt, a, hbt, s1L, s2L, e2g);
    hipLaunchKernelGGL(k_attn, dim3(256), dim3(512), 0, stream, mask, hbt, s1L, s2L, e2g, pS, pZ);
    hipLaunchKernelGGL(k_final, dim3(8192), dim3(256), 0, stream, pS, pZ, out);
}